// Round 4
// baseline (176.521 us; speedup 1.0000x reference)
//
#include <hip/hip_runtime.h>
#include <math.h>

#define FDIM 256
#define NH 8
#define HD 32
#define NQ 4096
#define NKEY 4096
#define CAP 512
#define R2 9.0f

typedef _Float16 half8 __attribute__((ext_vector_type(8)));
typedef _Float16 half4v __attribute__((ext_vector_type(4)));
typedef float f32x4 __attribute__((ext_vector_type(4)));
typedef unsigned short ushort_t;

// castbuf layout (f16 elements)
#define CB_CUR  0
#define CB_HIST 1048576
#define CB_WQ   2097152
#define CB_WK   2162688
#define CB_WV   2228224
#define CB_WO   2293760
#define CB_F4_TOTAL 589824  // total float4 groups (2359296 floats / 4)

// ---------------------------------------------------------------------------
// Cast all GEMM inputs fp32 -> fp16 into one contiguous buffer.
// ---------------------------------------------------------------------------
__global__ __launch_bounds__(256) void cast_all(const float* __restrict__ cur,
                                                const float* __restrict__ hist,
                                                const float* __restrict__ Wq,
                                                const float* __restrict__ Wk,
                                                const float* __restrict__ Wv,
                                                const float* __restrict__ Wo,
                                                _Float16* __restrict__ dst) {
    const int stride = gridDim.x * blockDim.x;
    for (int i4 = blockIdx.x * blockDim.x + threadIdx.x; i4 < CB_F4_TOTAL; i4 += stride) {
        const float* src;
        int base;
        if (i4 < 262144)      { src = cur;  base = 0; }
        else if (i4 < 524288) { src = hist; base = 262144; }
        else if (i4 < 540672) { src = Wq;   base = 524288; }
        else if (i4 < 557056) { src = Wk;   base = 540672; }
        else if (i4 < 573440) { src = Wv;   base = 557056; }
        else                  { src = Wo;   base = 573440; }
        float4 v = ((const float4*)src)[i4 - base];
        half4v h;
        h[0] = (_Float16)v.x; h[1] = (_Float16)v.y;
        h[2] = (_Float16)v.z; h[3] = (_Float16)v.w;
        ((half4v*)dst)[i4] = h;
    }
}

// ---------------------------------------------------------------------------
// MFMA GEMM core: C[m][n] = sum_k A[m][k] * W[n][k]  (A,W fp16 row-major,
// K=256). Wave tile 16(M)x64(N), no LDS; A-frag lane map A[m=lane&15]
// [k=quad*8+j], B-frag = 8 contiguous f16 of a W row. C/D: row=quad*4+r,
// col=lane&15.
// ---------------------------------------------------------------------------
__device__ __forceinline__ void mfma_tile_16x64(const _Float16* __restrict__ A,
                                                const _Float16* __restrict__ W,
                                                int m0, int n0, int wave, int lane,
                                                f32x4 acc[4]) {
    const int row  = lane & 15;
    const int quad = lane >> 4;
    const _Float16* aptr = A + (size_t)(m0 + wave * 16 + row) * 256 + quad * 8;
    const _Float16* wptr = W + (size_t)(n0 + row) * 256 + quad * 8;
#pragma unroll
    for (int i = 0; i < 4; ++i) acc[i] = (f32x4){0.f, 0.f, 0.f, 0.f};
#pragma unroll
    for (int k0 = 0; k0 < 8; ++k0) {
        half8 a = *(const half8*)(aptr + k0 * 32);
#pragma unroll
        for (int nt = 0; nt < 4; ++nt) {
            half8 b = *(const half8*)(wptr + (size_t)nt * 16 * 256 + k0 * 32);
            acc[nt] = __builtin_amdgcn_mfma_f32_16x16x32_f16(a, b, acc[nt], 0, 0, 0);
        }
    }
}

// Fused QKV projection. z=0: Q fp32 out (row-major [q][256]).
// z=1/2: K/V fp16 into head-major KV2[h][k][32 K | 32 V]  (128B per (h,k)).
__global__ __launch_bounds__(256) void qkv_mfma(const _Float16* __restrict__ cb,
                                                const float* __restrict__ bq,
                                                const float* __restrict__ bk,
                                                const float* __restrict__ bv,
                                                float* __restrict__ Qout,
                                                _Float16* __restrict__ KV2) {
    const int z    = blockIdx.z;
    const int wave = threadIdx.x >> 6;
    const int lane = threadIdx.x & 63;
    const int m0   = blockIdx.y * 64;
    const int n0   = blockIdx.x * 64;

    const _Float16* A = (z == 0) ? (cb + CB_CUR) : (cb + CB_HIST);
    const _Float16* W = (z == 0) ? (cb + CB_WQ) : (z == 1) ? (cb + CB_WK) : (cb + CB_WV);
    const float* bias = (z == 0) ? bq : (z == 1) ? bk : bv;

    f32x4 acc[4];
    mfma_tile_16x64(A, W, m0, n0, wave, lane, acc);

    const int col  = lane & 15;
    const int quad = lane >> 4;
    float bs[4];
#pragma unroll
    for (int nt = 0; nt < 4; ++nt) bs[nt] = bias[n0 + nt * 16 + col];

    if (z == 0) {
#pragma unroll
        for (int nt = 0; nt < 4; ++nt)
#pragma unroll
            for (int r = 0; r < 4; ++r)
                Qout[(size_t)(m0 + wave * 16 + quad * 4 + r) * 256 + n0 + nt * 16 + col] =
                    acc[nt][r] + bs[nt];
    } else {
        const int zoff = (z == 1) ? 0 : 32;
#pragma unroll
        for (int nt = 0; nt < 4; ++nt) {
            const int n  = n0 + nt * 16 + col;
            const int hh = n >> 5;
            const int d  = n & 31;
#pragma unroll
            for (int r = 0; r < 4; ++r) {
                const int k = m0 + wave * 16 + quad * 4 + r;
                KV2[(((size_t)hh * NKEY + k) << 6) + zoff + d] =
                    (_Float16)(acc[nt][r] + bs[nt]);
            }
        }
    }
}

// O-projection: out fp32 = Ob_f16 * Wo_f16^T + bo
__global__ __launch_bounds__(256) void o_mfma(const _Float16* __restrict__ Ob,
                                              const _Float16* __restrict__ Wo,
                                              const float* __restrict__ bo,
                                              float* __restrict__ out) {
    const int wave = threadIdx.x >> 6;
    const int lane = threadIdx.x & 63;
    const int m0   = blockIdx.y * 64;
    const int n0   = blockIdx.x * 64;

    f32x4 acc[4];
    mfma_tile_16x64(Ob, Wo, m0, n0, wave, lane, acc);

    const int col  = lane & 15;
    const int quad = lane >> 4;
#pragma unroll
    for (int nt = 0; nt < 4; ++nt) {
        const float b = bo[n0 + nt * 16 + col];
#pragma unroll
        for (int r = 0; r < 4; ++r)
            out[(size_t)(m0 + wave * 16 + quad * 4 + r) * 256 + n0 + nt * 16 + col] =
                acc[nt][r] + b;
    }
}

// ---------------------------------------------------------------------------
// Neighbor list build: exact reference fp32 arithmetic order (no contraction).
// ---------------------------------------------------------------------------
__global__ __launch_bounds__(256) void build_nbr(const float* __restrict__ qc,
                                                 const float* __restrict__ kc,
                                                 ushort_t* __restrict__ nbr,
                                                 int* __restrict__ cnt) {
    const int q    = blockIdx.x * 4 + (threadIdx.x >> 6);
    const int lane = threadIdx.x & 63;
    const float qx = qc[q * 3 + 0];
    const float qy = qc[q * 3 + 1];
    const float qz = qc[q * 3 + 2];
    int base = 0;
    for (int k0 = 0; k0 < NKEY; k0 += 64) {
        const int k = k0 + lane;
        float dx = __fsub_rn(qx, kc[k * 3 + 0]);
        float dy = __fsub_rn(qy, kc[k * 3 + 1]);
        float dz = __fsub_rn(qz, kc[k * 3 + 2]);
        float d2 = __fadd_rn(__fadd_rn(__fmul_rn(dx, dx), __fmul_rn(dy, dy)),
                             __fmul_rn(dz, dz));
        bool valid = (d2 <= R2);
        unsigned long long bal = __ballot(valid);
        if (valid) {
            int pos = base + __popcll(bal & ((1ull << lane) - 1ull));
            if (pos < CAP) nbr[(size_t)q * CAP + pos] = (ushort_t)k;
        }
        base += __popcll(bal);
    }
    if (lane == 0) cnt[q] = (base > CAP) ? CAP : base;
}

// ---------------------------------------------------------------------------
// Sparse attention v4: wave per query, lane = h*8 + j.
// Each lane computes FULL 32-dim dots + V accumulation for its own neighbor
// stream (j, j+8, ...) of head h -> no cross-lane ops in the loop, 64
// independent online-softmax chains per wave, 8 neighbors in flight/head.
// KV2[h][k] = 128B (32 f16 K | 32 f16 V) = one cache line per visit.
// Epilogue: 3-step shuffle butterfly merges the 8 lanes of each head.
// ---------------------------------------------------------------------------
__global__ __launch_bounds__(256) void sparse_attn4(const float* __restrict__ Q,
                                                    const _Float16* __restrict__ KV2,
                                                    const ushort_t* __restrict__ nbr,
                                                    const int* __restrict__ cnt,
                                                    _Float16* __restrict__ Ob) {
    const int q    = blockIdx.x * 4 + (threadIdx.x >> 6);
    const int lane = threadIdx.x & 63;
    const int h    = lane >> 3;  // head 0..7
    const int j0   = lane & 7;   // neighbor sub-stream 0..7

    // full 32-dim q vector for head h, pre-scaled
    float qv[32];
    {
        const float* qrow = Q + (size_t)q * FDIM + h * HD;
#pragma unroll
        for (int i = 0; i < 8; ++i) {
            float4 t = ((const float4*)qrow)[i];
            qv[i * 4 + 0] = t.x * 0.17677669529663687f;
            qv[i * 4 + 1] = t.y * 0.17677669529663687f;
            qv[i * 4 + 2] = t.z * 0.17677669529663687f;
            qv[i * 4 + 3] = t.w * 0.17677669529663687f;
        }
    }

    float o[32];
#pragma unroll
    for (int i = 0; i < 32; ++i) o[i] = 0.f;
    float m = -3e38f, l = 0.f;

    const int n = cnt[q];
    const ushort_t* nl = nbr + (size_t)q * CAP;
    const _Float16* hb = KV2 + ((size_t)h * NKEY << 6);

    for (int j = j0; j < n; j += 8) {
        const int k = nl[j];
        const _Float16* r = hb + ((size_t)k << 6);
        half8 k0v = ((const half8*)r)[0];
        half8 k1v = ((const half8*)r)[1];
        half8 k2v = ((const half8*)r)[2];
        half8 k3v = ((const half8*)r)[3];
        half8 v0v = ((const half8*)r)[4];
        half8 v1v = ((const half8*)r)[5];
        half8 v2v = ((const half8*)r)[6];
        half8 v3v = ((const half8*)r)[7];

        float p0 = 0.f, p1 = 0.f, p2 = 0.f, p3 = 0.f;
#pragma unroll
        for (int i = 0; i < 8; ++i) {
            p0 = fmaf(qv[i],      (float)k0v[i], p0);
            p1 = fmaf(qv[8 + i],  (float)k1v[i], p1);
            p2 = fmaf(qv[16 + i], (float)k2v[i], p2);
            p3 = fmaf(qv[24 + i], (float)k3v[i], p3);
        }
        const float sc = (p0 + p1) + (p2 + p3);

        const float nm = fmaxf(m, sc);
        const float sf = __expf(m - nm);
        const float pw = __expf(sc - nm);
        l = l * sf + pw;
#pragma unroll
        for (int i = 0; i < 8; ++i) {
            o[i]      = o[i]      * sf + pw * (float)v0v[i];
            o[8 + i]  = o[8 + i]  * sf + pw * (float)v1v[i];
            o[16 + i] = o[16 + i] * sf + pw * (float)v2v[i];
            o[24 + i] = o[24 + i] * sf + pw * (float)v3v[i];
        }
        m = nm;
    }

    // butterfly-merge the 8 sub-streams of this head (lanes h*8 .. h*8+7)
#pragma unroll
    for (int d = 1; d < 8; d <<= 1) {
        const float m2 = __shfl_xor(m, d, 64);
        const float l2 = __shfl_xor(l, d, 64);
        const float nm = fmaxf(m, m2);
        const float a  = __expf(m - nm);   // -3e38-finite underflows to 0
        const float b  = __expf(m2 - nm);
        l = l * a + l2 * b;
#pragma unroll
        for (int i = 0; i < 32; ++i) {
            const float o2 = __shfl_xor(o[i], d, 64);
            o[i] = o[i] * a + o2 * b;
        }
        m = nm;
    }

    if (j0 == 0) {
        const float inv = 1.0f / l;  // l==0 (no neighbors) -> inf -> NaN, matches ref
        _Float16* orow = Ob + (size_t)q * FDIM + h * HD;
#pragma unroll
        for (int w8 = 0; w8 < 4; ++w8) {
            half8 ho;
#pragma unroll
            for (int i = 0; i < 8; ++i) ho[i] = (_Float16)(o[w8 * 8 + i] * inv);
            ((half8*)orow)[w8] = ho;
        }
    }
}

// ---------------------------------------------------------------------------
extern "C" void kernel_launch(void* const* d_in, const int* in_sizes, int n_in,
                              void* d_out, int out_size, void* d_ws, size_t ws_size,
                              hipStream_t stream) {
    const float* cur_feats   = (const float*)d_in[0];
    const float* hist_feats  = (const float*)d_in[1];
    const float* cur_coords  = (const float*)d_in[2];
    const float* hist_coords = (const float*)d_in[3];
    const float* bq = (const float*)d_in[5];
    const float* bk = (const float*)d_in[7];
    const float* bv = (const float*)d_in[9];
    const float* bo = (const float*)d_in[11];
    float* out = (float*)d_out;

    char* w = (char*)d_ws;
    float*     Qb   = (float*)(w);                         // 4 MiB fp32
    _Float16*  KV2  = (_Float16*)(w + (4 << 20));          // 8 heads x 4096 x 128B = 4 MiB
    ushort_t*  nbr  = (ushort_t*)(w + (8 << 20));          // 4 MiB
    int*       cnt  = (int*)(w + (12 << 20));              // 16 KiB
    _Float16*  Ob   = (_Float16*)(w + (12 << 20) + (64 << 10));  // 2 MiB
    _Float16*  cb   = (_Float16*)(w + (15 << 20));         // cast buffer ~4.5 MiB

    cast_all<<<1024, 256, 0, stream>>>(cur_feats, hist_feats,
                                       (const float*)d_in[4], (const float*)d_in[6],
                                       (const float*)d_in[8], (const float*)d_in[10], cb);

    build_nbr<<<NQ / 4, 256, 0, stream>>>(cur_coords, hist_coords, nbr, cnt);

    qkv_mfma<<<dim3(4, 64, 3), 256, 0, stream>>>(cb, bq, bk, bv, Qb, KV2);

    sparse_attn4<<<NQ / 4, 256, 0, stream>>>(Qb, KV2, nbr, cnt, Ob);

    o_mfma<<<dim3(4, 64), 256, 0, stream>>>(Ob, cb + CB_WO, bo, out);
}

// Round 6
// 150.130 us; speedup vs baseline: 1.1758x; 1.1758x over previous
//
#include <hip/hip_runtime.h>
#include <math.h>

#define FDIM 256
#define NH 8
#define HD 32
#define NQ 4096
#define NKEY 4096
#define CAP 512
#define R2 9.0f

typedef _Float16 half8 __attribute__((ext_vector_type(8)));
typedef _Float16 half4v __attribute__((ext_vector_type(4)));
typedef float f32x4 __attribute__((ext_vector_type(4)));
typedef unsigned short ushort_t;

// castbuf layout (f16 elements)
#define CB_CUR  0
#define CB_HIST 1048576
#define CB_WQ   2097152
#define CB_WK   2162688
#define CB_WV   2228224
#define CB_WO   2293760
#define CB_F4_TOTAL 589824  // total float4 groups (2359296 floats / 4)

// ---------------------------------------------------------------------------
// prep: blocks [0,1024) build the neighbor lists; blocks [1024,2048) cast all
// GEMM inputs fp32->fp16 (grid-stride). Fused to save a launch.
// ---------------------------------------------------------------------------
__global__ __launch_bounds__(256) void prep(const float* __restrict__ cur,
                                            const float* __restrict__ hist,
                                            const float* __restrict__ Wq,
                                            const float* __restrict__ Wk,
                                            const float* __restrict__ Wv,
                                            const float* __restrict__ Wo,
                                            _Float16* __restrict__ dst,
                                            const float* __restrict__ qc,
                                            const float* __restrict__ kc,
                                            ushort_t* __restrict__ nbr,
                                            int* __restrict__ cnt) {
    if (blockIdx.x < 1024) {
        // ---- neighbor build: exact reference fp32 op order (no contraction)
        const int q    = blockIdx.x * 4 + (threadIdx.x >> 6);
        const int lane = threadIdx.x & 63;
        const float qx = qc[q * 3 + 0];
        const float qy = qc[q * 3 + 1];
        const float qz = qc[q * 3 + 2];
        int base = 0;
        for (int k0 = 0; k0 < NKEY; k0 += 64) {
            const int k = k0 + lane;
            float dx = __fsub_rn(qx, kc[k * 3 + 0]);
            float dy = __fsub_rn(qy, kc[k * 3 + 1]);
            float dz = __fsub_rn(qz, kc[k * 3 + 2]);
            float d2 = __fadd_rn(__fadd_rn(__fmul_rn(dx, dx), __fmul_rn(dy, dy)),
                                 __fmul_rn(dz, dz));
            bool valid = (d2 <= R2);
            unsigned long long bal = __ballot(valid);
            if (valid) {
                int pos = base + __popcll(bal & ((1ull << lane) - 1ull));
                if (pos < CAP) nbr[(size_t)q * CAP + pos] = (ushort_t)k;
            }
            base += __popcll(bal);
        }
        if (lane == 0) cnt[q] = (base > CAP) ? CAP : base;
    } else {
        // ---- fp32 -> fp16 cast of feats + weights
        const int stride = 1024 * 256;
        for (int i4 = (blockIdx.x - 1024) * 256 + threadIdx.x; i4 < CB_F4_TOTAL;
             i4 += stride) {
            const float* src;
            int base;
            if (i4 < 262144)      { src = cur;  base = 0; }
            else if (i4 < 524288) { src = hist; base = 262144; }
            else if (i4 < 540672) { src = Wq;   base = 524288; }
            else if (i4 < 557056) { src = Wk;   base = 540672; }
            else if (i4 < 573440) { src = Wv;   base = 557056; }
            else                  { src = Wo;   base = 573440; }
            float4 v = ((const float4*)src)[i4 - base];
            half4v h;
            h[0] = (_Float16)v.x; h[1] = (_Float16)v.y;
            h[2] = (_Float16)v.z; h[3] = (_Float16)v.w;
            ((half4v*)dst)[i4] = h;
        }
    }
}

// ---------------------------------------------------------------------------
// MFMA GEMM core: C[m][n] = sum_k A[m][k] * W[n][k]  (f16 row-major, K=256).
// Wave tile 16x64, no LDS. A-frag A[m=lane&15][k=quad*8+j]; B-frag = 8
// contiguous f16 of a W row. C/D: row=quad*4+r, col=lane&15.
// ---------------------------------------------------------------------------
__device__ __forceinline__ void mfma_tile_16x64(const _Float16* __restrict__ A,
                                                const _Float16* __restrict__ W,
                                                int m0, int n0, int wave, int lane,
                                                f32x4 acc[4]) {
    const int row  = lane & 15;
    const int quad = lane >> 4;
    const _Float16* aptr = A + (size_t)(m0 + wave * 16 + row) * 256 + quad * 8;
    const _Float16* wptr = W + (size_t)(n0 + row) * 256 + quad * 8;
#pragma unroll
    for (int i = 0; i < 4; ++i) acc[i] = (f32x4){0.f, 0.f, 0.f, 0.f};
#pragma unroll
    for (int k0 = 0; k0 < 8; ++k0) {
        half8 a = *(const half8*)(aptr + k0 * 32);
#pragma unroll
        for (int nt = 0; nt < 4; ++nt) {
            half8 b = *(const half8*)(wptr + (size_t)nt * 16 * 256 + k0 * 32);
            acc[nt] = __builtin_amdgcn_mfma_f32_16x16x32_f16(a, b, acc[nt], 0, 0, 0);
        }
    }
}

// Fused QKV. z=0: Q fp32 out. z=1/2: K/V f16 into row-major interleaved
// KV[k][0:256]=K, KV[k][256:512]=V (half-wave row loads coalesce).
__global__ __launch_bounds__(256) void qkv_mfma(const _Float16* __restrict__ cb,
                                                const float* __restrict__ bq,
                                                const float* __restrict__ bk,
                                                const float* __restrict__ bv,
                                                float* __restrict__ Qout,
                                                _Float16* __restrict__ KV) {
    const int z    = blockIdx.z;
    const int wave = threadIdx.x >> 6;
    const int lane = threadIdx.x & 63;
    const int m0   = blockIdx.y * 64;
    const int n0   = blockIdx.x * 64;

    const _Float16* A = (z == 0) ? (cb + CB_CUR) : (cb + CB_HIST);
    const _Float16* W = (z == 0) ? (cb + CB_WQ) : (z == 1) ? (cb + CB_WK) : (cb + CB_WV);
    const float* bias = (z == 0) ? bq : (z == 1) ? bk : bv;

    f32x4 acc[4];
    mfma_tile_16x64(A, W, m0, n0, wave, lane, acc);

    const int col  = lane & 15;
    const int quad = lane >> 4;
    float bs[4];
#pragma unroll
    for (int nt = 0; nt < 4; ++nt) bs[nt] = bias[n0 + nt * 16 + col];

    if (z == 0) {
#pragma unroll
        for (int nt = 0; nt < 4; ++nt)
#pragma unroll
            for (int r = 0; r < 4; ++r)
                Qout[(size_t)(m0 + wave * 16 + quad * 4 + r) * 256 + n0 + nt * 16 + col] =
                    acc[nt][r] + bs[nt];
    } else {
        const int off = (z == 1) ? 0 : 256;
#pragma unroll
        for (int nt = 0; nt < 4; ++nt)
#pragma unroll
            for (int r = 0; r < 4; ++r)
                KV[(size_t)(m0 + wave * 16 + quad * 4 + r) * 512 + off + n0 + nt * 16 + col] =
                    (_Float16)(acc[nt][r] + bs[nt]);
    }
}

// O-projection: out fp32 = Ob_f16 * Wo_f16^T + bo
__global__ __launch_bounds__(256) void o_mfma(const _Float16* __restrict__ Ob,
                                              const _Float16* __restrict__ Wo,
                                              const float* __restrict__ bo,
                                              float* __restrict__ out) {
    const int wave = threadIdx.x >> 6;
    const int lane = threadIdx.x & 63;
    const int m0   = blockIdx.y * 64;
    const int n0   = blockIdx.x * 64;

    f32x4 acc[4];
    mfma_tile_16x64(Ob, Wo, m0, n0, wave, lane, acc);

    const int col  = lane & 15;
    const int quad = lane >> 4;
#pragma unroll
    for (int nt = 0; nt < 4; ++nt) {
        const float b = bo[n0 + nt * 16 + col];
#pragma unroll
        for (int r = 0; r < 4; ++r)
            out[(size_t)(m0 + wave * 16 + quad * 4 + r) * 256 + n0 + nt * 16 + col] =
                acc[nt][r] + b;
    }
}

// ---------------------------------------------------------------------------
// Sparse attention v6: ONE BLOCK (4 waves) PER QUERY.
// lane = p*32 + h*4 + s. Half-wave p of wave w handles neighbor stream
// j = 2w+p, +8, ... (8 streams). Each load instruction covers 2 contiguous
// 512B KV row segments (coalesced). Each lane holds dims [8s,8s+8) of head h;
// the full 32-dim score is restored by shfl_xor(1)+shfl_xor(2) across the 4
// s-lanes (the v5 bug was omitting this). fp32 q, mixed-precision fma dot.
// Epilogue: shfl(32) p-merge, then 4-way LDS merge across waves.
// ---------------------------------------------------------------------------
__global__ __launch_bounds__(256) void sparse_attn6(const float* __restrict__ Q,
                                                    const _Float16* __restrict__ KV,
                                                    const ushort_t* __restrict__ nbr,
                                                    const int* __restrict__ cnt,
                                                    _Float16* __restrict__ Ob) {
    __shared__ float sm[4][32][12];
    const int q    = blockIdx.x;
    const int t    = threadIdx.x;
    const int wave = t >> 6;
    const int lane = t & 63;
    const int p    = lane >> 5;
    const int h    = (lane >> 2) & 7;
    const int s    = lane & 3;

    // 8-dim q slice for (h,s), pre-scaled by 1/sqrt(HD), fp32
    float qv[8];
    {
        const float* qrow = Q + (size_t)q * FDIM + h * HD + s * 8;
        float4 a = ((const float4*)qrow)[0];
        float4 b = ((const float4*)qrow)[1];
        const float sc = 0.17677669529663687f;
        qv[0] = a.x * sc; qv[1] = a.y * sc; qv[2] = a.z * sc; qv[3] = a.w * sc;
        qv[4] = b.x * sc; qv[5] = b.y * sc; qv[6] = b.z * sc; qv[7] = b.w * sc;
    }

    float o[8];
#pragma unroll
    for (int i = 0; i < 8; ++i) o[i] = 0.f;
    float m = -3e38f, l = 0.f;

    const int n = cnt[q];
    const ushort_t* nl = nbr + (size_t)q * CAP;
    const int koff = h * HD + s * 8;

    for (int j = 2 * wave + p; j < n; j += 8) {
        const int k = nl[j];
        const _Float16* r = KV + ((size_t)k << 9) + koff;
        half8 k8 = *(const half8*)(r);
        half8 v8 = *(const half8*)(r + 256);

        float part = 0.f;
#pragma unroll
        for (int i = 0; i < 8; ++i)
            part = fmaf(qv[i], (float)k8[i], part);
        // full 32-dim score: reduce across the 4 s-lanes of this head
        part += __shfl_xor(part, 1, 64);
        part += __shfl_xor(part, 2, 64);

        const float nm = fmaxf(m, part);
        const float sf = __expf(m - nm);
        const float pw = __expf(part - nm);
        l = l * sf + pw;
#pragma unroll
        for (int i = 0; i < 8; ++i)
            o[i] = o[i] * sf + pw * (float)v8[i];
        m = nm;
    }

    // merge the two 32-lane halves (same (h,s), streams p=0/1)
    {
        const float m2 = __shfl_xor(m, 32, 64);
        const float l2 = __shfl_xor(l, 32, 64);
        const float nm = fmaxf(m, m2);
        const float a  = __expf(m - nm);
        const float b  = __expf(m2 - nm);
        l = l * a + l2 * b;
#pragma unroll
        for (int i = 0; i < 8; ++i) {
            const float o2 = __shfl_xor(o[i], 32, 64);
            o[i] = o[i] * a + o2 * b;
        }
        m = nm;
    }

    if (lane < 32) {  // lane == h*4+s
        float* dst = &sm[wave][lane][0];
        *(float4*)(dst)     = (float4){o[0], o[1], o[2], o[3]};
        *(float4*)(dst + 4) = (float4){o[4], o[5], o[6], o[7]};
        dst[8] = m; dst[9] = l;
    }
    __syncthreads();

    if (t < 32) {  // t == h*4+s ; output offset = 8*t
        float4 x0 = *(const float4*)&sm[0][t][0];
        float4 x1 = *(const float4*)&sm[0][t][4];
        float O[8] = {x0.x, x0.y, x0.z, x0.w, x1.x, x1.y, x1.z, x1.w};
        float M = sm[0][t][8], L = sm[0][t][9];
#pragma unroll
        for (int w = 1; w < 4; ++w) {
            float4 y0 = *(const float4*)&sm[w][t][0];
            float4 y1 = *(const float4*)&sm[w][t][4];
            const float m2 = sm[w][t][8], l2 = sm[w][t][9];
            const float nm = fmaxf(M, m2);
            const float a  = __expf(M - nm);
            const float b  = __expf(m2 - nm);
            L = L * a + l2 * b;
            float y[8] = {y0.x, y0.y, y0.z, y0.w, y1.x, y1.y, y1.z, y1.w};
#pragma unroll
            for (int i = 0; i < 8; ++i) O[i] = O[i] * a + y[i] * b;
            M = nm;
        }
        const float inv = 1.0f / L;
        half8 ho;
#pragma unroll
        for (int i = 0; i < 8; ++i) ho[i] = (_Float16)(O[i] * inv);
        *(half8*)(Ob + (size_t)q * FDIM + t * 8) = ho;
    }
}

// ---------------------------------------------------------------------------
extern "C" void kernel_launch(void* const* d_in, const int* in_sizes, int n_in,
                              void* d_out, int out_size, void* d_ws, size_t ws_size,
                              hipStream_t stream) {
    const float* cur_feats   = (const float*)d_in[0];
    const float* hist_feats  = (const float*)d_in[1];
    const float* cur_coords  = (const float*)d_in[2];
    const float* hist_coords = (const float*)d_in[3];
    const float* bq = (const float*)d_in[5];
    const float* bk = (const float*)d_in[7];
    const float* bv = (const float*)d_in[9];
    const float* bo = (const float*)d_in[11];
    float* out = (float*)d_out;

    char* w = (char*)d_ws;
    float*     Qb   = (float*)(w);                         // 4 MiB fp32
    _Float16*  KV   = (_Float16*)(w + (4 << 20));          // 4096 x 512 f16 = 4 MiB
    ushort_t*  nbr  = (ushort_t*)(w + (8 << 20));          // 4 MiB
    int*       cnt  = (int*)(w + (12 << 20));              // 16 KiB
    _Float16*  Ob   = (_Float16*)(w + (12 << 20) + (64 << 10));  // 2 MiB
    _Float16*  cb   = (_Float16*)(w + (15 << 20));         // cast buffer ~4.5 MiB

    prep<<<2048, 256, 0, stream>>>(cur_feats, hist_feats,
                                   (const float*)d_in[4], (const float*)d_in[6],
                                   (const float*)d_in[8], (const float*)d_in[10], cb,
                                   cur_coords, hist_coords, nbr, cnt);

    qkv_mfma<<<dim3(4, 64, 3), 256, 0, stream>>>(cb, bq, bk, bv, Qb, KV);

    sparse_attn6<<<NQ, 256, 0, stream>>>(Qb, KV, nbr, cnt, Ob);

    o_mfma<<<dim3(4, 64), 256, 0, stream>>>(Ob, cb + CB_WO, bo, out);
}